// Round 1
// baseline (307.364 us; speedup 1.0000x reference)
//
#include <hip/hip_runtime.h>
#include <stdint.h>

// Problem constants
#define BB 4
#define TT 2048
#define EE 1024
#define HH 16
#define DD 64
#define MM (BB*TT)        // 8192
#define NQKV (3*EE)       // 3072

typedef __bf16 bf16_t;
typedef bf16_t bf16x8 __attribute__((ext_vector_type(8)));
typedef short  s16x4  __attribute__((ext_vector_type(4)));
typedef float  floatx4 __attribute__((ext_vector_type(4)));

__device__ __forceinline__ unsigned short f2bf(float f) {
    unsigned int u = __float_as_uint(f);
    u = (u + 0x7FFFu + ((u >> 16) & 1u)) >> 16;
    return (unsigned short)u;
}

__device__ __forceinline__ void load_lds16(const void* g, void* l) {
    __builtin_amdgcn_global_load_lds(
        (const __attribute__((address_space(1))) unsigned int*)g,
        (__attribute__((address_space(3))) unsigned int*)l, 16, 0, 0);
}

// ---------------------------------------------------------------- convert
__global__ void cvt_f32_bf16(const float* __restrict__ in,
                             unsigned short* __restrict__ out, int n) {
    int i = (blockIdx.x * 256 + threadIdx.x) * 4;
    if (i + 3 < n) {
        float4 v = *reinterpret_cast<const float4*>(in + i);
        ushort4 o;
        o.x = f2bf(v.x); o.y = f2bf(v.y); o.z = f2bf(v.z); o.w = f2bf(v.w);
        *reinterpret_cast<ushort4*>(out + i) = o;
    }
}

// ---------------------------------------------------------------- GEMM 256x256 8-phase
// C[M][N] = A[M][K=1024] * Bw[N][K]^T. BM=BN=256, BK=64, 512 thr = 8 waves (2M x 4N),
// per-wave 128x64 (M_rep=8, N_rep=4) -> 43.7 FLOP/LDS-byte > 31.8 machine ratio.
// LDS: ring of 4 K-half slots per operand ([256][32] bf16 = 16KB each) = 128 KiB total,
// 1 block/CU. 64B row stride keeps frag ds_read_b128 uniformly bank-spread (no swizzle).
// Schedule (T3+T4): 4 phases/K-tile, 16 MFMA each; stage steps for tile kt+2 issued in
// kt's P2/P3 (into kt's just-vacated slots); counted waits vmcnt(8) end-P1 (covers h1),
// vmcnt(12) end-P3 (covers next tile h0). NEVER vmcnt(0) except the kt=15 peel.
// Raw s_barrier only (no __syncthreads -> no compiler vmcnt(0) drain); every barrier has
// a compile-time memory fence so LDS reads can't hoist across the vmcnt/barrier pairs.
// T5: setprio(1) around each MFMA cluster. T1: XCD swizzle (nwg%8==0 for 384 and 128).
#define VW(N) asm volatile("s_waitcnt vmcnt(" #N ")" ::: "memory")
#define BARX() do { __builtin_amdgcn_s_barrier(); asm volatile("" ::: "memory"); } while (0)
#define FR(p, t) (*reinterpret_cast<const bf16x8*>((p) + (t) * 512))
#define MFMA1(mi, ni, av, bv) \
    acc[mi][ni] = __builtin_amdgcn_mfma_f32_16x16x32_bf16(av, bv, acc[mi][ni], 0, 0, 0)
#define MFMA_BLK(M0) do { \
    MFMA1(M0+0,0,a0,b0); MFMA1(M0+0,1,a0,b1); MFMA1(M0+0,2,a0,b2); MFMA1(M0+0,3,a0,b3); \
    MFMA1(M0+1,0,a1,b0); MFMA1(M0+1,1,a1,b1); MFMA1(M0+1,2,a1,b2); MFMA1(M0+1,3,a1,b3); \
    MFMA1(M0+2,0,a2,b0); MFMA1(M0+2,1,a2,b1); MFMA1(M0+2,2,a2,b2); MFMA1(M0+2,3,a2,b3); \
    MFMA1(M0+3,0,a3,b0); MFMA1(M0+3,1,a3,b1); MFMA1(M0+3,2,a3,b2); MFMA1(M0+3,3,a3,b3); \
} while (0)
// stage one K-half region (256 rows x 32 cols): 2 x global_load_lds_dwordx4 per thread.
// LDS dest chunk = j*512 + w*64 + lane (wave-uniform base + lane*16 by HW); global src
// row = j*128 + (tid>>2), col-chunk = tid&3 -> matches linear LDS layout exactly.
#define STEP_A(kt_, h_) do { \
    const unsigned short* _g = Ag + (kt_) * 64 + (h_) * 32; \
    unsigned short* _l = (unsigned short*)&As[(2*(kt_)+(h_)) & 3][w * 512]; \
    load_lds16(_g, _l); \
    load_lds16(_g + (size_t)128 * 1024, _l + 4096); \
} while (0)
#define STEP_B(kt_, h_) do { \
    const unsigned short* _g = Bg + (kt_) * 64 + (h_) * 32; \
    unsigned short* _l = (unsigned short*)&Bs[(2*(kt_)+(h_)) & 3][w * 512]; \
    load_lds16(_g, _l); \
    load_lds16(_g + (size_t)128 * 1024, _l + 4096); \
} while (0)
// one K-tile: P0 {read h0 frags; 16 MFMA} P1 {read af4-7 h0; 16 MFMA; vmcnt} P2/P3 same
// for h1 with stage-issues for kt+2 placed AFTER the mid barrier (WAR-safe vs other
// waves' reads of the slot being overwritten).
#define TILE_BODY(kt_, W1CODE, W3CODE, DOISS) do { \
    const int _s0 = (2 * (kt_)) & 3; \
    const unsigned short* _ap0 = &As[_s0][aoff]; \
    const unsigned short* _bp0 = &Bs[_s0][boff]; \
    const unsigned short* _ap1 = &As[_s0 + 1][aoff]; \
    const unsigned short* _bp1 = &Bs[_s0 + 1][boff]; \
    bf16x8 a0, a1, a2, a3, b0, b1, b2, b3; \
    a0 = FR(_ap0, 0); a1 = FR(_ap0, 1); a2 = FR(_ap0, 2); a3 = FR(_ap0, 3); \
    b0 = FR(_bp0, 0); b1 = FR(_bp0, 1); b2 = FR(_bp0, 2); b3 = FR(_bp0, 3); \
    BARX(); __builtin_amdgcn_s_setprio(1); MFMA_BLK(0); __builtin_amdgcn_s_setprio(0); BARX(); \
    a0 = FR(_ap0, 4); a1 = FR(_ap0, 5); a2 = FR(_ap0, 6); a3 = FR(_ap0, 7); \
    BARX(); __builtin_amdgcn_s_setprio(1); MFMA_BLK(4); __builtin_amdgcn_s_setprio(0); W1CODE; BARX(); \
    a0 = FR(_ap1, 0); a1 = FR(_ap1, 1); a2 = FR(_ap1, 2); a3 = FR(_ap1, 3); \
    b0 = FR(_bp1, 0); b1 = FR(_bp1, 1); b2 = FR(_bp1, 2); b3 = FR(_bp1, 3); \
    BARX(); __builtin_amdgcn_s_setprio(1); \
    if (DOISS) { STEP_A((kt_) + 2, 0); STEP_B((kt_) + 2, 0); } \
    MFMA_BLK(0); __builtin_amdgcn_s_setprio(0); BARX(); \
    a0 = FR(_ap1, 4); a1 = FR(_ap1, 5); a2 = FR(_ap1, 6); a3 = FR(_ap1, 7); \
    BARX(); __builtin_amdgcn_s_setprio(1); \
    if (DOISS) { STEP_A((kt_) + 2, 1); STEP_B((kt_) + 2, 1); } \
    MFMA_BLK(4); __builtin_amdgcn_s_setprio(0); W3CODE; BARX(); \
} while (0)

// EPI 0: qkv epilogue (scatter q/k/v, fold splat-scale * 1/sqrt(D) into q, bf16).
// EPI 1: fp32 + bias to Cout. K = 1024 for both GEMMs in this problem.
template<int N, int EPI>
__global__ __launch_bounds__(512, 2) void gemm256(
    const unsigned short* __restrict__ A,
    const unsigned short* __restrict__ Bw,
    const float* __restrict__ bias,
    const float* __restrict__ sscale,
    unsigned short* __restrict__ Qb,
    unsigned short* __restrict__ Kb,
    unsigned short* __restrict__ Vtb,
    float* __restrict__ Cout)
{
    __shared__ __align__(16) unsigned short As[4][8192];   // 4 K-half slots, 256r x 32c
    __shared__ __align__(16) unsigned short Bs[4][8192];

    const int tid  = threadIdx.x;
    const int lane = tid & 63;
    const int w    = tid >> 6;
    const int quad = lane >> 4;
    const int l16  = lane & 15;

    // T1: XCD-aware swizzle (384%8==0, 128%8==0 -> bijective simple form).
    const int nwg = (int)gridDim.x;
    const int wg  = ((int)blockIdx.x & 7) * (nwg >> 3) + ((int)blockIdx.x >> 3);
    const int nbx = N / 256;
    const int m0  = (wg / nbx) * 256;
    const int n0  = (wg % nbx) * 256;

    const int wm = (w >> 2) * 128;    // wave row offset: 0 or 128
    const int wn = (w & 3) * 64;      // wave col offset: 0/64/128/192

    // staging thread-constants: row = tid>>2 (+128 for 2nd call), col-chunk = tid&3
    const int srow = tid >> 2;
    const int scol = (tid & 3) * 8;
    const unsigned short* Ag = A  + (size_t)(m0 + srow) * 1024 + scol;
    const unsigned short* Bg = Bw + (size_t)(n0 + srow) * 1024 + scol;

    // fragment read offsets (ushort units): row*32 + quad*8, +mt*512 per 16 rows
    const int aoff = (wm + l16) * 32 + quad * 8;
    const int boff = (wn + l16) * 32 + quad * 8;

    floatx4 acc[8][4] = {};

    // prologue: tiles 0 and 1 (slots 0..3), then wait for tile0-h0 (6 newer steps = 12)
    STEP_A(0, 0); STEP_B(0, 0); STEP_A(0, 1); STEP_B(0, 1);
    STEP_A(1, 0); STEP_B(1, 0); STEP_A(1, 1); STEP_B(1, 1);
    VW(12); BARX();

#pragma unroll 2
    for (int kt = 0; kt < 14; ++kt) {
        TILE_BODY(kt, VW(8), VW(12), 1);
    }
    TILE_BODY(14, VW(8), VW(4), 0);     // tail: only s(15,2..3) newer at P3
    TILE_BODY(15, VW(0), (void)0, 0);   // tail: drain for own h1, nothing after

    // epilogue: C layout col = l16, row = quad*4 + r (verified mapping)
    if (EPI == 0) {
        const int colb  = n0 + wn;
        const int which = colb >> 10;   // uniform per block (256 | 1024)
#pragma unroll
        for (int nt = 0; nt < 4; ++nt) {
            const int col = colb + nt * 16 + l16;
            const int e = col & 1023;
            const int hh = e >> 6, d = e & 63;
            const float bsv = bias[col];
            float qs = 0.f;
            if (which == 0) qs = (1.0f + 0.01f * tanhf(sscale[hh])) * 0.125f;
#pragma unroll
            for (int mt = 0; mt < 8; ++mt) {
                const int rowb = m0 + wm + mt * 16 + quad * 4;
#pragma unroll
                for (int r = 0; r < 4; ++r) {
                    const int m = rowb + r;           // b*T + t
                    const int b = m >> 11, t = m & 2047;
                    const size_t bh = (size_t)(b * HH + hh);
                    float v = acc[mt][nt][r] + bsv;
                    if (which == 0) {
                        Qb[(bh * TT + t) * DD + d] = f2bf(v * qs);
                    } else if (which == 1) {
                        Kb[(bh * TT + t) * DD + d] = f2bf(v);
                    } else {
                        Vtb[(bh * DD + d) * TT + t] = f2bf(v);
                    }
                }
            }
        }
    } else {
#pragma unroll
        for (int mt = 0; mt < 8; ++mt) {
            const int rowb = m0 + wm + mt * 16 + quad * 4;
#pragma unroll
            for (int nt = 0; nt < 4; ++nt) {
                const int col = n0 + wn + nt * 16 + l16;
                const float bsv = bias[col];
#pragma unroll
                for (int r = 0; r < 4; ++r)
                    Cout[(size_t)(rowb + r) * N + col] = acc[mt][nt][r] + bsv;
            }
        }
    }
}

// ---------------------------------------------------------------- flash attention v6
// (unchanged this round) Grid: 2048 blocks = (32 q-tiles of 64 rows) x (64 bh).
#define LP 72   // padded LDS row stride: 144B -> dword stride 36, 2-way max conflicts
__global__ __launch_bounds__(256, 4) void flash_attn(
    const unsigned short* __restrict__ Qb,
    const unsigned short* __restrict__ Kb,
    const unsigned short* __restrict__ Vtb,
    unsigned short* __restrict__ Ob)
{
    __shared__ __align__(16) unsigned short Ks[2][64 * LP];   // [buf][key][d]
    __shared__ __align__(16) unsigned short Vs[2][64 * LP];   // [buf][d][key]

    const int tid  = threadIdx.x;
    const int lane = tid & 63;
    const int w    = tid >> 6;
    const int quad = lane >> 4;
    const int l16  = lane & 15;
    const int i    = blockIdx.x;
    const int bh   = i & 63;               // 0..63
    const int qt   = 31 - (i >> 6);        // 0..31, heavy first
    const int row0 = qt * 64 + w * 16;     // wave's first q row

    const unsigned short* qbase = &Qb[((size_t)bh * TT + row0 + l16) * DD + quad * 8];
    const bf16x8 qf0 = *reinterpret_cast<const bf16x8*>(qbase);
    const bf16x8 qf1 = *reinterpret_cast<const bf16x8*>(qbase + 32);

    const s16x4 vones = { (short)0x3F80, (short)0x3F80, (short)0x3F80, (short)0x3F80 };

    floatx4 o[4] = {};
    floatx4 o1 = {};   // row sums

    const int srow = tid >> 3;            // 0..31
    const int scol = (tid & 7) * 8;       // 0..56
    const size_t kgbase = ((size_t)bh * TT + srow) * DD + scol;
    const size_t vgbase = ((size_t)bh * DD + srow) * TT + scol;

    uint4 kr0 = *reinterpret_cast<const uint4*>(&Kb[kgbase]);
    uint4 kr1 = *reinterpret_cast<const uint4*>(&Kb[kgbase + 32 * DD]);
    uint4 vr0 = *reinterpret_cast<const uint4*>(&Vtb[vgbase]);
    uint4 vr1 = *reinterpret_cast<const uint4*>(&Vtb[vgbase + 32 * TT]);

    for (int kt = 0; kt <= qt; ++kt) {
        const int buf = kt & 1;
        *reinterpret_cast<uint4*>(&Ks[buf][srow * LP + scol]) = kr0;
        *reinterpret_cast<uint4*>(&Ks[buf][(srow + 32) * LP + scol]) = kr1;
        *reinterpret_cast<uint4*>(&Vs[buf][srow * LP + scol]) = vr0;
        *reinterpret_cast<uint4*>(&Vs[buf][(srow + 32) * LP + scol]) = vr1;
        __syncthreads();

        if (kt < qt) {
            size_t ko = kgbase + (size_t)(kt + 1) * 64 * DD;
            size_t vo = vgbase + (size_t)(kt + 1) * 64;
            kr0 = *reinterpret_cast<const uint4*>(&Kb[ko]);
            kr1 = *reinterpret_cast<const uint4*>(&Kb[ko + 32 * DD]);
            vr0 = *reinterpret_cast<const uint4*>(&Vtb[vo]);
            vr1 = *reinterpret_cast<const uint4*>(&Vtb[vo + 32 * TT]);
        }

        const int keyb = kt * 64 + quad * 4;
        const int qr0  = row0 + l16;
        const bool diag = (kt == qt);

#pragma unroll
        for (int ntk = 0; ntk < 4; ++ntk) {
            const unsigned short* krow = &Ks[buf][(ntk * 16 + l16) * LP + quad * 8];
            bf16x8 kf0 = *reinterpret_cast<const bf16x8*>(krow);
            bf16x8 kf1 = *reinterpret_cast<const bf16x8*>(krow + 32);

            floatx4 st = {0.f, 0.f, 0.f, 0.f};
            st = __builtin_amdgcn_mfma_f32_16x16x32_bf16(kf0, qf0, st, 0, 0, 0);
            st = __builtin_amdgcn_mfma_f32_16x16x32_bf16(kf1, qf1, st, 0, 0, 0);

            s16x4 pf;
#pragma unroll
            for (int r = 0; r < 4; ++r) {
                float p = __expf(st[r]);
                pf[r] = (short)((!diag || (keyb + ntk * 16 + r <= qr0)) ? f2bf(p) : 0);
            }

            o1 = __builtin_amdgcn_mfma_f32_16x16x16bf16_1k(pf, vones, o1, 0, 0, 0);
#pragma unroll
            for (int dt = 0; dt < 4; ++dt) {
                s16x4 vf = *reinterpret_cast<const s16x4*>(
                    &Vs[buf][(dt * 16 + l16) * LP + ntk * 16 + quad * 4]);
                o[dt] = __builtin_amdgcn_mfma_f32_16x16x16bf16_1k(pf, vf, o[dt], 0, 0, 0);
            }
        }
    }

    const int b = bh >> 4, h = bh & 15;
#pragma unroll
    for (int r = 0; r < 4; ++r) {
        int q = row0 + quad * 4 + r;
        float rl = __builtin_amdgcn_rcpf(o1[r]);
#pragma unroll
        for (int dt = 0; dt < 4; ++dt)
            Ob[((size_t)(b * TT + q)) * EE + h * DD + dt * 16 + l16] =
                f2bf(o[dt][r] * rl);
    }
}

// ---------------------------------------------------------------- launch
extern "C" void kernel_launch(void* const* d_in, const int* in_sizes, int n_in,
                              void* d_out, int out_size, void* d_ws, size_t ws_size,
                              hipStream_t stream) {
    const float* hs    = (const float*)d_in[0];
    const float* Wqkv  = (const float*)d_in[1];
    const float* bqkv  = (const float*)d_in[2];
    const float* Wproj = (const float*)d_in[3];
    const float* bproj = (const float*)d_in[4];
    const float* ss    = (const float*)d_in[5];
    // d_in[6] = splat_bias: softmax-invariant (uniform shift of unmasked logits), unused
    float* out = (float*)d_out;

    char* p = (char*)d_ws;
    unsigned short* hsb    = (unsigned short*)p; p += (size_t)MM * EE * 2;      // 16.8 MB (reused as ctx)
    unsigned short* wqkvb  = (unsigned short*)p; p += (size_t)NQKV * EE * 2;    //  6.3 MB
    unsigned short* wprojb = (unsigned short*)p; p += (size_t)EE * EE * 2;      //  2.1 MB
    unsigned short* Qb     = (unsigned short*)p; p += (size_t)BB*HH*TT*DD * 2;  // 16.8 MB
    unsigned short* Kb     = (unsigned short*)p; p += (size_t)BB*HH*TT*DD * 2;  // 16.8 MB
    unsigned short* Vtb    = (unsigned short*)p; p += (size_t)BB*HH*TT*DD * 2;  // 16.8 MB

    cvt_f32_bf16<<<(MM * EE) / 1024, 256, 0, stream>>>(hs, hsb, MM * EE);
    cvt_f32_bf16<<<(NQKV * EE) / 1024, 256, 0, stream>>>(Wqkv, wqkvb, NQKV * EE);
    cvt_f32_bf16<<<(EE * EE) / 1024, 256, 0, stream>>>(Wproj, wprojb, EE * EE);

    gemm256<NQKV, 0><<<dim3((MM / 256) * (NQKV / 256)), 512, 0, stream>>>(
        hsb, wqkvb, bqkv, ss, Qb, Kb, Vtb, nullptr);

    flash_attn<<<dim3(2048), 256, 0, stream>>>(Qb, Kb, Vtb, hsb);

    gemm256<EE, 1><<<dim3((MM / 256) * (EE / 256)), 512, 0, stream>>>(
        hsb, wprojb, bproj, nullptr, nullptr, nullptr, nullptr, out);
}